// Round 3
// baseline (431.125 us; speedup 1.0000x reference)
//
#include <hip/hip_runtime.h>
#include <math.h>

#define NEGINF (-INFINITY)
#define SENT 300   // "no cached column" sentinel (> any real col)

// One DPP max stage: x = max(x, lanes-moved(x)). old=x + bound_ctrl=false makes
// invalid source lanes contribute x (identity for max).
template <int CTRL>
__device__ __forceinline__ float dppmax(float x) {
    int xi = __float_as_int(x);
    int yi = __builtin_amdgcn_update_dpp(xi, xi, CTRL, 0xf, 0xf, false);
    return fmaxf(x, __int_as_float(yi));
}

// Wave64 max via DPP: row_shr 1/2/4/8 + row_bcast 15/31 -> lane 63, then readlane.
__device__ __forceinline__ float wave_max64(float x) {
    x = dppmax<0x111>(x);
    x = dppmax<0x112>(x);
    x = dppmax<0x114>(x);
    x = dppmax<0x118>(x);
    x = dppmax<0x142>(x);
    x = dppmax<0x143>(x);
    return __int_as_float(__builtin_amdgcn_readlane(__float_as_int(x), 63));
}

// Wave argmax over (v, idx), tie-break lowest idx (jnp.argmax first-occurrence).
__device__ __forceinline__ void wave_argmax(float v, int idx, float& out_v, int& out_idx) {
    float mv = wave_max64(v);
    unsigned long long mask = __ballot(v == mv);
    int ln = (int)__builtin_ctzll(mask);
    int bi = __builtin_amdgcn_readlane(idx, ln);
    unsigned long long rest = mask & (mask - 1);
    if (rest) {                      // ties across lanes: rare
        while (rest) {
            int l2 = (int)__builtin_ctzll(rest); rest &= rest - 1;
            int b2 = __builtin_amdgcn_readlane(idx, l2);
            if (b2 < bi) bi = b2;
        }
    }
    out_v = mv; out_idx = bi;
}

// One wave per batch. Lane l owns rows {j*64+l}. Per row: cached top-2 over
// untaken columns. Column mask replicated in all lanes (cm0..cm3).
__global__ __launch_bounds__(64, 1) void greedy_perm_kernel(
        const float* __restrict__ soft, float* __restrict__ out) {
    const int lane = threadIdx.x;
    const size_t base = (size_t)blockIdx.x << 16;
    const float* sc = soft + base;
    float* ob = out + base;

    float v1[4], v2[4];
    int   c1[4], c2[4];
#pragma unroll
    for (int j = 0; j < 4; ++j) { v1[j] = NEGINF; c1[j] = 0; v2[j] = NEGINF; c2[j] = 0; }

    const float4 zero4 = make_float4(0.f, 0.f, 0.f, 0.f);

    // ---- initial per-row top-2 scans (16 loads in flight) + fused zero-fill ----
    for (int k = 0; k < 64; k += 4) {
        float4 w[4][4];
#pragma unroll
        for (int j = 0; j < 4; ++j) {
            const float4* rp = (const float4*)(sc + (size_t)(j * 64 + lane) * 256);
#pragma unroll
            for (int kk = 0; kk < 4; ++kk) w[j][kk] = rp[k + kk];
        }
#pragma unroll
        for (int j = 0; j < 4; ++j) {
            float4* op = (float4*)(ob + (size_t)(j * 64 + lane) * 256);
#pragma unroll
            for (int kk = 0; kk < 4; ++kk) op[k + kk] = zero4;
        }
#pragma unroll
        for (int j = 0; j < 4; ++j) {
#pragma unroll
            for (int kk = 0; kk < 4; ++kk) {
                const float4 ww = w[j][kk];
                const float e[4] = {ww.x, ww.y, ww.z, ww.w};
#pragma unroll
                for (int q = 0; q < 4; ++q) {
                    const float wv = e[q];
                    const int   x  = 4 * (k + kk) + q;
                    if (wv > v1[j])      { v2[j] = v1[j]; c2[j] = c1[j]; v1[j] = wv; c1[j] = x; }
                    else if (wv > v2[j]) { v2[j] = wv; c2[j] = x; }
                }
            }
        }
    }
    __threadfence_block();   // zero-stores drained before any 1.0 store

    unsigned long long cm0 = 0, cm1 = 0, cm2 = 0, cm3 = 0;  // replicated col mask

    // ---- 256 sequential greedy steps ----
    for (int step = 0; step < 256; ++step) {
        // local best over 4 owned rows (flat = row*256+col; dead rows never win)
        float bv = v1[0]; int bf = (lane << 8) | (c1[0] & 255);
#pragma unroll
        for (int j = 1; j < 4; ++j) {
            int f = ((j * 64 + lane) << 8) | (c1[j] & 255);
            if (v1[j] > bv || (v1[j] == bv && f < bf)) { bv = v1[j]; bf = f; }
        }
        float gv; int gf;
        wave_argmax(bv, bf, gv, gf);
        const int r = gf >> 8, cc = gf & 255;

        if (lane == 0) ob[(size_t)gf] = 1.0f;

        // mark column cc taken (wave-uniform)
        {
            const unsigned long long bit = 1ull << (cc & 63);
            const int wsel = cc >> 6;
            if (wsel == 0) cm0 |= bit; else if (wsel == 1) cm1 |= bit;
            else if (wsel == 2) cm2 |= bit; else cm3 |= bit;
        }
        // retire row r (its owner lane)
#pragma unroll
        for (int j = 0; j < 4; ++j)
            if (r == j * 64 + lane) { v1[j] = NEGINF; c1[j] = SENT; v2[j] = NEGINF; c2[j] = SENT; }

        // per-lane fallback: rows whose cached argmax col was just taken
        unsigned need = 0;
#pragma unroll
        for (int j = 0; j < 4; ++j) {
            if (c1[j] == cc) {
                bool ok = false;
                const int cx = c2[j];
                if (cx != SENT) {
                    const int ws = cx >> 6;
                    const unsigned long long cw = ws == 0 ? cm0 : ws == 1 ? cm1 : ws == 2 ? cm2 : cm3;
                    ok = ((cw >> (cx & 63)) & 1ull) == 0;
                }
                if (ok) { v1[j] = v2[j]; c1[j] = cx; v2[j] = NEGINF; c2[j] = SENT; }
                else    need |= 1u << j;
            }
        }

        // cooperative full rescans (both cached cols gone) — recompute top-2
#pragma unroll
        for (int j = 0; j < 4; ++j) {
            unsigned long long m = __ballot((need >> j) & 1u);
            while (m) {
                const int ln = (int)__builtin_ctzll(m); m &= m - 1;
                const int row = j * 64 + ln;
                // coalesced: 64 lanes x float4 = whole row
                float4 w = *(const float4*)(sc + (size_t)row * 256 + lane * 4);
                const int wsel = lane >> 4;
                const unsigned long long cw = wsel == 0 ? cm0 : wsel == 1 ? cm1 : wsel == 2 ? cm2 : cm3;
                const unsigned nib = (unsigned)(cw >> ((lane & 15) * 4)) & 15u;
                float m0 = (nib & 1u) ? NEGINF : w.x;
                float m1 = (nib & 2u) ? NEGINF : w.y;
                float m2 = (nib & 4u) ? NEGINF : w.z;
                float m3 = (nib & 8u) ? NEGINF : w.w;
                float lv = m0; int lf = 4 * lane + 0;
                if (m1 > lv) { lv = m1; lf = 4 * lane + 1; }
                if (m2 > lv) { lv = m2; lf = 4 * lane + 2; }
                if (m3 > lv) { lv = m3; lf = 4 * lane + 3; }
                float rv1; int rf1;
                wave_argmax(lv, lf, rv1, rf1);
                // second max: mask out rf1, reduce again
                if ((rf1 >> 2) == lane) {
                    const int q = rf1 & 3;
                    if (q == 0) m0 = NEGINF; else if (q == 1) m1 = NEGINF;
                    else if (q == 2) m2 = NEGINF; else m3 = NEGINF;
                }
                lv = m0; lf = 4 * lane + 0;
                if (m1 > lv) { lv = m1; lf = 4 * lane + 1; }
                if (m2 > lv) { lv = m2; lf = 4 * lane + 2; }
                if (m3 > lv) { lv = m3; lf = 4 * lane + 3; }
                float rv2; int rf2;
                wave_argmax(lv, lf, rv2, rf2);
                if (lane == ln) {
                    v1[j] = rv1; c1[j] = rf1;
                    if (rv2 == NEGINF) { v2[j] = NEGINF; c2[j] = SENT; }
                    else               { v2[j] = rv2;    c2[j] = rf2;  }
                }
            }
        }
    }
}

extern "C" void kernel_launch(void* const* d_in, const int* in_sizes, int n_in,
                              void* d_out, int out_size, void* d_ws, size_t ws_size,
                              hipStream_t stream) {
    const float* soft = (const float*)d_in[0];
    float* out = (float*)d_out;
    const int n_batches = in_sizes[0] >> 16;   // elements / (256*256)
    greedy_perm_kernel<<<n_batches, 64, 0, stream>>>(soft, out);
}